// Round 7
// baseline (225.000 us; speedup 1.0000x reference)
//
#include <hip/hip_runtime.h>
#include <hip/hip_bf16.h>
#include <math.h>

#define L 2048
#define NH 10
#define DP 32
#define D30 30

typedef __attribute__((ext_vector_type(8))) short bf16x8;
typedef __attribute__((ext_vector_type(4))) float f32x4;

__device__ inline short f2bf(float f) {
    union { float f; unsigned u; } v; v.f = f;
    unsigned r = (v.u + 0x7FFF + ((v.u >> 16) & 1)) >> 16;
    return (short)r;
}
// pack two floats to packed bf16x2 (HW cvt if available)
__device__ inline unsigned pkbf(float a, float b) {
#if __has_builtin(__builtin_amdgcn_cvt_pk_bf16_f32)
    typedef __attribute__((ext_vector_type(2))) __bf16 bf2;
    union { bf2 v; unsigned u; } x;
    x.v = __builtin_amdgcn_cvt_pk_bf16_f32(a, b);
    return x.u;
#else
    unsigned ua = __float_as_uint(a) + 0x8000u;
    unsigned ub = __float_as_uint(b) + 0x8000u;
    return (ua >> 16) | (ub & 0xFFFF0000u);
#endif
}
// K-order permutation within 64-chunks (shared by P-tile and Vt layout)
__device__ inline int permL(int l) {
    return (l & ~63) | ((l & 15) << 2) | ((l >> 4) & 3);
}

#define GLD16(g, l) __builtin_amdgcn_global_load_lds( \
    (__attribute__((address_space(1))) void*)(g),     \
    (__attribute__((address_space(3))) void*)(l), 16, 0, 0)

// ---------------- Projection kernel (bf16 MFMA) + wo16/ones conversion (og=5) -
__global__ __launch_bounds__(256) void proj_kernel(
    const float* __restrict__ x, const float* __restrict__ ax,
    const float* __restrict__ wq, const float* __restrict__ bq,
    const float* __restrict__ wk, const float* __restrict__ bk,
    const float* __restrict__ wv, const float* __restrict__ bv,
    const float* __restrict__ wo, short* __restrict__ wo16,
    short* __restrict__ Kbuf, short* __restrict__ Vbuf, short* __restrict__ Vtbuf)
{
    const int t  = threadIdx.x;
    const int og = blockIdx.y;       // 0..4 proj, 5 = wo16 + Vt-ones
    const int b  = blockIdx.z;

    if (og == 5) {
        int id = (b * 32 + blockIdx.x) * 256 + t;
        if (id < 20480) {
            // wo -> bf16 padded [256][320]
            int idx = id * 4;
            int o = idx / 320, c = idx % 320;
            float v0 = (c + 0 < 300) ? wo[o * 300 + c + 0] : 0.f;
            float v1 = (c + 1 < 300) ? wo[o * 300 + c + 1] : 0.f;
            float v2 = (c + 2 < 300) ? wo[o * 300 + c + 2] : 0.f;
            float v3 = (c + 3 < 300) ? wo[o * 300 + c + 3] : 0.f;
            uint2 u; u.x = pkbf(v0, v1); u.y = pkbf(v2, v3);
            *(uint2*)&wo16[idx] = u;
            // Vt ones row d=30 (lsum-via-MFMA trick): 40 bh * 2048 l = 20480*4
            int j = id * 4;
            int bh = j >> 11, l = j & 2047;
            uint2 one; one.x = 0x3F803F80u; one.y = 0x3F803F80u;
            *(uint2*)&Vtbuf[((size_t)bh * DP + 30) * L + l] = one;
        }
        return;
    }

    __shared__ __align__(16) short Wl[112 * 72];   // [o][64c], stride 72 (pad)
    __shared__ __align__(16) short XT[64 * 72];    // [l][64c], stride 72
    const int l0 = blockIdx.x * 64;

    const float* W; const float* bias;
    if (og == 0)      { W = wq; bias = bq; }
    else if (og <= 2) { W = wk; bias = bk; }
    else              { W = wv; bias = bv; }
    const int al = (og - 1) & 1;

    const int wid  = t >> 6;
    const int lane = t & 63;
    const int quad = lane >> 4;
    const int l15  = lane & 15;

    f32x4 acc[7];
    #pragma unroll
    for (int ot = 0; ot < 7; ot++) acc[ot] = (f32x4){0,0,0,0};

    const int rs = (og == 0) ? L : (2 * L);        // c-row stride
    const float* srcb = (og == 0)
        ? x  + (size_t)(b * 256) * L
        : ax + ((size_t)(b * 256) * 2 + al) * L;
    const int lx = t & 31;     // l col for X staging
    const int px = t >> 5;     // 0..7 c-pair group

    for (int cc = 0; cc < 4; cc++) {
        const int c0 = cc * 64;
        __syncthreads();
        // stage W chunk [112 x 64] fp32 -> bf16 (coalesced; rows >=100 zero)
        #pragma unroll
        for (int it = 0; it < 7; it++) {
            int kk = (t + it * 256) * 4;
            int o = kk >> 6, c = kk & 63;
            f32x4 v = {0, 0, 0, 0};
            if (o < 100) v = *(const f32x4*)(W + (size_t)o * 256 + c0 + c);
            uint2 u; u.x = pkbf(v[0], v[1]); u.y = pkbf(v[2], v[3]);
            *(uint2*)&Wl[o * 72 + c] = u;
        }
        // stage X^T [64 l x 64 c]: 4 passes, row-coalesced reads (128B segments)
        #pragma unroll
        for (int ps = 0; ps < 4; ps++) {
            int c = (ps * 8 + px) * 2;             // local c, c+1
            const float* s = srcb + (size_t)(c0 + c) * rs + l0;
            float a0 = s[lx],      a1 = s[rs + lx];
            float b0 = s[lx + 32], b1 = s[rs + lx + 32];
            *(unsigned*)&XT[lx * 72 + c]        = pkbf(a0, a1);
            *(unsigned*)&XT[(lx + 32) * 72 + c] = pkbf(b0, b1);
        }
        __syncthreads();
        #pragma unroll
        for (int ks = 0; ks < 2; ks++) {
            bf16x8 bfrag = *(const bf16x8*)&XT[(wid * 16 + l15) * 72 + ks * 32 + quad * 8];
            #pragma unroll
            for (int ot = 0; ot < 7; ot++) {
                bf16x8 afrag = *(const bf16x8*)&Wl[(ot * 16 + l15) * 72 + ks * 32 + quad * 8];
                acc[ot] = __builtin_amdgcn_mfma_f32_16x16x32_bf16(afrag, bfrag, acc[ot], 0, 0, 0);
            }
        }
    }

    const int part = (og == 0) ? 0 : ((og == 1 || og == 3) ? 1 : 2);
    const float KS = 0.31622776601683794f * 1.4426950408889634f;  // scale*log2e
    const int l = l0 + wid * 16 + l15;
    #pragma unroll
    for (int ot = 0; ot < 7; ot++) {
        #pragma unroll
        for (int r = 0; r < 4; r++) {
            int o = ot * 16 + quad * 4 + r;
            if (o >= 100) continue;
            float val = acc[ot][r] + bias[o];
            int h = o / 10, dd = 3 * (o % 10) + part;
            size_t rowb = ((size_t)(b * NH + h)) * L;
            size_t tb   = ((size_t)(b * NH + h) * DP + dd) * L;
            if (og == 0) {
                Kbuf[(rowb + l) * DP + dd] = f2bf(val * KS);
                short s = f2bf(val);
                Vbuf[(rowb + l) * DP + dd] = s;
                Vtbuf[tb + permL(l)] = s;
            } else if (og <= 2) {
                Kbuf[(rowb + l) * DP + dd] = f2bf(val * KS);
            } else {
                short s = f2bf(val);
                Vbuf[(rowb + l) * DP + dd] = s;
                Vtbuf[tb + permL(l)] = s;
            }
        }
    }
}

// ---------------- Flash attention: lsum via Vt-ones row, raw-flat output ------
__global__ __launch_bounds__(256, 5) void attn_kernel(
    const short* __restrict__ K, const short* __restrict__ V,
    const short* __restrict__ Vt, const float* __restrict__ edge,
    float* __restrict__ Opart, float* __restrict__ lsums, int npart)
{
    __shared__ __align__(16) short Vl[2][64 * 32];    // [head][m][d swizzled]
    __shared__ __align__(16) short Vtl[2][32 * 64];   // [head][d][m swizzled]
    __shared__ __align__(16) short Pm[4][16 * 72];    // per-wave P tile
    const int t    = threadIdx.x;
    const int wid  = t >> 6;
    const int lane = t & 63;
    const int quad = lane >> 4;
    const int l15  = lane & 15;

    const int id  = blockIdx.x;
    const int gg  = id / 40;
    const int rem = id - gg * 40;
    const int h2  = rem >> 3;
    const int g   = gg * 8 + (rem & 7);
    const int lb  = g & 31;
    const int b   = (g >> 5) & 3;
    const int mz  = g >> 7;

    const int l0 = lb * 64;
    const int h0 = h2 * 2;
    const size_t bh0 = (size_t)(b * NH + h0), bh1 = bh0 + 1;
    const int mbase = mz * (L / npart);
    const int nit   = (L / npart) / 64;

    const int lrow = l0 + wid * 16 + l15;
    bf16x8 kf[2];
    kf[0] = *(const bf16x8*)(K + (bh0 * L + lrow) * DP + quad * 8);
    kf[1] = *(const bf16x8*)(K + (bh1 * L + lrow) * DP + quad * 8);

    const int myrow = l0 + wid * 16 + quad * 4;
    const float* ep[4];
    #pragma unroll
    for (int r = 0; r < 4; r++)
        ep[r] = edge + (size_t)b * L * L + (size_t)(myrow + r) * L + l15 + mbase;

    const int sh = wid & 1;
    const size_t sbh = bh0 + sh;
    const short* sgp;
    if (wid < 2)
        sgp = V + (sbh * L + mbase + (lane >> 2)) * DP + (((lane & 3) ^ ((lane >> 3) & 3)) * 8);
    else
        sgp = Vt + (sbh * DP + (lane >> 3)) * L + mbase + (((lane & 7) ^ ((lane >> 3) & 7)) * 8);

    f32x4 O[2][2] = {{{0,0,0,0},{0,0,0,0}},{{0,0,0,0},{0,0,0,0}}};
    const f32x4 z = {0,0,0,0};

    for (int mt = 0; mt < nit; mt++) {
        __syncthreads();                     // prior LDS reads done
        if (wid < 2) {
            #pragma unroll
            for (int k = 0; k < 4; k++)
                GLD16(sgp + k * (16 * DP), &Vl[sh][k * 512]);
        } else {
            #pragma unroll
            for (int k = 0; k < 4; k++)
                GLD16(sgp + (size_t)k * (8 * L), &Vtl[sh][k * 512]);
        }
        float e[4][4];
        #pragma unroll
        for (int r = 0; r < 4; r++)
            #pragma unroll
            for (int nb = 0; nb < 4; nb++)
                e[nb][r] = ep[r][nb * 16];
        __syncthreads();                     // tiles + edge ready

        short* P = &Pm[wid][0];
        #pragma unroll
        for (int hh = 0; hh < 2; hh++) {
            f32x4 S[4];
            #pragma unroll
            for (int nb = 0; nb < 4; nb++) {
                int sw = (quad ^ ((l15 >> 1) & 3)) * 8;
                bf16x8 vf = *(const bf16x8*)&Vl[hh][(nb * 16 + l15) * 32 + sw];
                S[nb] = __builtin_amdgcn_mfma_f32_16x16x32_bf16(kf[hh], vf, z, 0, 0, 0);
            }
            #pragma unroll
            for (int r = 0; r < 4; r++) {
                float p0 = __builtin_amdgcn_exp2f(S[0][r] * e[0][r]);
                float p1 = __builtin_amdgcn_exp2f(S[1][r] * e[1][r]);
                float p2 = __builtin_amdgcn_exp2f(S[2][r] * e[2][r]);
                float p3 = __builtin_amdgcn_exp2f(S[3][r] * e[3][r]);
                uint2 u; u.x = pkbf(p0, p1); u.y = pkbf(p2, p3);
                *(uint2*)&P[(quad * 4 + r) * 72 + l15 * 4] = u;   // k' = l15*4+nb
            }
            #pragma unroll
            for (int ks = 0; ks < 2; ks++) {
                int go = ((ks * 4 + quad) ^ (l15 & 7)) * 8;
                bf16x8 a  = *(const bf16x8*)&P[l15 * 72 + ks * 32 + quad * 8];
                bf16x8 b0 = *(const bf16x8*)&Vtl[hh][l15 * 64 + go];
                bf16x8 b1 = *(const bf16x8*)&Vtl[hh][(16 + l15) * 64 + go];
                O[hh][0] = __builtin_amdgcn_mfma_f32_16x16x32_bf16(a, b0, O[hh][0], 0, 0, 0);
                O[hh][1] = __builtin_amdgcn_mfma_f32_16x16x32_bf16(a, b1, O[hh][1], 0, 0, 0);
            }
        }
        #pragma unroll
        for (int r = 0; r < 4; r++) ep[r] += 64;
        sgp += (wid < 2) ? 64 * DP : 64;
    }

    // epilogue: raw torch-view flat layout [h*61440 + l*30 + d]; lane14 of
    // O[.][1] is d=30 = ones column = lsum.
    float* ab  = Opart + (size_t)mz * 2457600 + (size_t)b * 614400;
    float* lsp = lsums + (size_t)mz * 81920  + (size_t)b * 20480;
    #pragma unroll
    for (int r = 0; r < 4; r++) {
        int lr = myrow + r;
        size_t base0 = (size_t)h0 * 61440 + (size_t)lr * 30;
        ab[base0 + l15]         = O[0][0][r];
        ab[base0 + 61440 + l15] = O[1][0][r];
        if (l15 < 14) {
            ab[base0 + 16 + l15]         = O[0][1][r];
            ab[base0 + 61440 + 16 + l15] = O[1][1][r];
        }
        if (l15 == 14) {
            lsp[h0 * L + lr]       = O[0][1][r];
            lsp[(h0 + 1) * L + lr] = O[1][1][r];
        }
    }
}

// ---------------- Output projection (bf16 MFMA), fused combine+normalize ------
// out[b,o,m] = bo[o] + sum_c wo[o,c] * ((P0[f]+P1[f]) / (ls0[f/30]+ls1[f/30])),
// f = c*2048+m (raw torch-view flat index within batch).
__global__ __launch_bounds__(256, 4) void out_kernel(
    const float* __restrict__ Opart, const float* __restrict__ lsums,
    const short* __restrict__ wo16, const float* __restrict__ bo,
    float* __restrict__ out, int npart)
{
    __shared__ __align__(16) short XT[32 * 72];   // [m][c-chunk], stride 72
    const int t    = threadIdx.x;
    const int wid  = t >> 6;
    const int lane = t & 63;
    const int quad = lane >> 4;
    const int l15  = lane & 15;
    const int m0 = blockIdx.x * 32;
    const int o0 = blockIdx.y * 64;
    const int b  = blockIdx.z;
    const float* P0b = Opart + (size_t)b * 614400;
    const float* P1b = Opart + 2457600 + (size_t)b * 614400;
    const float* ls0 = lsums + (size_t)b * 20480;
    const float* ls1 = lsums + 81920 + (size_t)b * 20480;

    f32x4 acc0 = {0,0,0,0}, acc1 = {0,0,0,0};
    const int cb = t >> 4;    // 0..15 -> 4 c-rows each
    const int mb = t & 15;    // m pair
    const short* wrow = wo16 + (size_t)(o0 + wid * 16 + l15) * 320;

    for (int cc = 0; cc < 5; cc++) {
        const int c0 = cc * 64;
        __syncthreads();
        {   // stage XT[32 m][64 c]: partial-sum + normalize + bf16 pack
            int crb = c0 + cb * 4;
            float vx[4], vy[4];
            #pragma unroll
            for (int i = 0; i < 4; i++) {
                int cr = crb + i; if (cr > 299) cr = 299;  // W rows >=300 are 0
                int f = cr * 2048 + m0 + mb * 2;
                float2 p = *(const float2*)(P0b + f);
                int j0 = f / 30, j1 = (f + 1) / 30;
                float s0 = ls0[j0], s1 = ls0[j1];
                if (npart == 2) {
                    float2 q = *(const float2*)(P1b + f);
                    p.x += q.x; p.y += q.y;
                    s0 += ls1[j0]; s1 += ls1[j1];
                }
                vx[i] = p.x * __builtin_amdgcn_rcpf(s0);
                vy[i] = p.y * __builtin_amdgcn_rcpf(s1);
            }
            uint2 u0; u0.x = pkbf(vx[0], vx[1]); u0.y = pkbf(vx[2], vx[3]);
            *(uint2*)&XT[(mb * 2 + 0) * 72 + cb * 4] = u0;
            uint2 u1; u1.x = pkbf(vy[0], vy[1]); u1.y = pkbf(vy[2], vy[3]);
            *(uint2*)&XT[(mb * 2 + 1) * 72 + cb * 4] = u1;
        }
        __syncthreads();
        #pragma unroll
        for (int ks = 0; ks < 2; ks++) {
            bf16x8 a  = *(const bf16x8*)(wrow + c0 + ks * 32 + quad * 8);
            bf16x8 b0 = *(const bf16x8*)&XT[l15 * 72 + ks * 32 + quad * 8];
            bf16x8 b1 = *(const bf16x8*)&XT[(16 + l15) * 72 + ks * 32 + quad * 8];
            acc0 = __builtin_amdgcn_mfma_f32_16x16x32_bf16(a, b0, acc0, 0, 0, 0);
            acc1 = __builtin_amdgcn_mfma_f32_16x16x32_bf16(a, b1, acc1, 0, 0, 0);
        }
    }
    #pragma unroll
    for (int r = 0; r < 4; r++) {
        int o = o0 + wid * 16 + quad * 4 + r;
        float bb = bo[o];
        float* orow = out + ((size_t)(b * 256 + o)) * L;
        orow[m0 + l15]      = acc0[r] + bb;
        orow[m0 + 16 + l15] = acc1[r] + bb;
    }
}

extern "C" void kernel_launch(void* const* d_in, const int* in_sizes, int n_in,
                              void* d_out, int out_size, void* d_ws, size_t ws_size,
                              hipStream_t stream) {
    const float* x    = (const float*)d_in[0];
    const float* ax   = (const float*)d_in[1];
    const float* edge = (const float*)d_in[2];
    const float* wq   = (const float*)d_in[3];
    const float* bq   = (const float*)d_in[4];
    const float* wk   = (const float*)d_in[5];
    const float* bk   = (const float*)d_in[6];
    const float* wv   = (const float*)d_in[7];
    const float* bv   = (const float*)d_in[8];
    const float* wo   = (const float*)d_in[9];
    const float* bo   = (const float*)d_in[10];
    float* out = (float*)d_out;

    const size_t KB  = (size_t)4 * NH * L * DP * 2;  // 5,242,880 per bf16 buffer
    const size_t PSZ = (size_t)2457600 * 4;
    const size_t LSZ = (size_t)81920 * 4;
    const size_t WOS = (size_t)256 * 320 * 2;
    char* ws = (char*)d_ws;
    short* Kbuf  = (short*)ws;
    short* Vbuf  = (short*)(ws + KB);
    short* Vtbuf = (short*)(ws + 2 * KB);
    float* P0    = (float*)(ws + 3 * KB);
    int npart = (ws_size >= 3 * KB + 2 * PSZ + 2 * LSZ + WOS) ? 2 : 1;
    float* lsums = (float*)(ws + 3 * KB + (size_t)npart * PSZ);
    short* wo16  = (short*)(ws + 3 * KB + (size_t)npart * (PSZ + LSZ));
    if (ws_size < 3 * KB + PSZ + LSZ + WOS) return;

    hipMemsetAsync(ws, 0, 3 * KB, stream);           // zero pad cols d=30,31

    proj_kernel<<<dim3(32, 6, 4), 256, 0, stream>>>(x, ax, wq, bq, wk, bk, wv, bv,
                                                    wo, wo16, Kbuf, Vbuf, Vtbuf);
    attn_kernel<<<dim3(640 * npart), 256, 0, stream>>>(Kbuf, Vbuf, Vtbuf, edge,
                                                       P0, lsums, npart);
    out_kernel<<<dim3(64, 4, 4), 256, 0, stream>>>(P0, lsums, wo16, bo, out, npart);
}